// Round 20
// baseline (53.977 us; speedup 1.0000x reference)
//
#include <hip/hip_runtime.h>
#include <math.h>

// NonlocalWeightedAverage via MX-scaled fp8 MFMA (K=64), fixed-reference
// softmax. corr[m,n] = <lf_m, lf_n>, lf = 3x3-unfolded feature, K = 9*64.
// R20: R17's proven body (2-gen SP, 120 VGPR, no spill) split q=2 ways over
// yn so GRID = 512 = 2 blocks/CU -> 4 waves/SIMD. R17 was latency-bound:
// only ~52% of cycles had any pipe busy at 2 waves/SIMD (grid 256 = 1
// block/CU was the residency limiter; 68KB LDS x2 fits 160KB, 120 VGPR x16
// waves fits the 2048-reg pool). Two independent blocks/CU interleave across
// each other's barriers. Partial-state merge kernel returns (2 q-partials).

#define B_ 4
#define CH 64
#define H_ 64
#define W_ 64
#define SCALE2 14.426950408889634f   // (1/ALPHA=10) * log2(e)
#define STRIPE 1056                  // 66 xx * 16 B
#define ROWB (4 * STRIPE)            // 4224 B: one feature row (fp8)
#define NRING 6

typedef __attribute__((ext_vector_type(4)))  unsigned int uint4v;
typedef __attribute__((ext_vector_type(16))) float f32x16;
typedef __attribute__((ext_vector_type(8)))  int int8v;

__device__ inline void glds16(const void* g, void* l) {
    __builtin_amdgcn_global_load_lds(
        (const __attribute__((address_space(1))) unsigned int*)g,
        (__attribute__((address_space(3))) unsigned int*)l, 16, 0, 0);
}

// decode OCP e4m3fn (NaN never occurs for our data: |f| <= ~5 << 448)
__device__ inline float dec_e4m3(unsigned u) {
    unsigned e = (u >> 3) & 15u, m = u & 7u;
    float v = e ? __uint_as_float(((e + 120u) << 23) | (m << 20))
                : (float)m * 0x1p-9f;
    return (u & 0x80u) ? -v : v;
}

// feat [B,C,H,W] f32 -> tf [B,H,W,64] fp8 e4m3 (fragment-pair packed), plus
// per-pixel channel-norm^2 of the DECODED fp8 values -> n2 [B,H,W].
__global__ __launch_bounds__(256) void feat_to_fp8(
    const float* __restrict__ feat, unsigned char* __restrict__ tf,
    float* __restrict__ n2)
{
    const int b = blockIdx.y, y = blockIdx.x, t = (int)threadIdx.x;
    __shared__ float ld[CH][W_ + 1];
    #pragma unroll
    for (int i = 0; i < 16; ++i) {
        int idx = i * 256 + t;
        int c = idx >> 6, x = idx & 63;
        ld[c][x] = feat[(((size_t)b * CH + c) * H_ + y) * W_ + x];
    }
    __syncthreads();
    const int x = t >> 2, g = t & 3;
    const int cbase = (g >> 1) * 32 + (g & 1) * 8;
    unsigned int wd[4];
    #pragma unroll
    for (int w4 = 0; w4 < 4; ++w4) {
        float f[4];
        #pragma unroll
        for (int e = 0; e < 4; ++e) {
            int j = w4 * 4 + e;
            f[e] = ld[cbase + ((j >> 3) << 4) + (j & 7)][x];
        }
        unsigned int wv = 0;
        wv = __builtin_amdgcn_cvt_pk_fp8_f32(f[0], f[1], wv, false);
        wv = __builtin_amdgcn_cvt_pk_fp8_f32(f[2], f[3], wv, true);
        wd[w4] = wv;
    }
    float s = 0.f;
    #pragma unroll
    for (int w4 = 0; w4 < 4; ++w4)
        #pragma unroll
        for (int e = 0; e < 4; ++e) {
            float d = dec_e4m3((wd[w4] >> (8 * e)) & 0xffu);
            s = fmaf(d, d, s);
        }
    s += __shfl_xor(s, 1);
    s += __shfl_xor(s, 2);
    if (g == 0) n2[((size_t)b * H_ + y) * W_ + x] = s;

    unsigned char* dst = tf + (((size_t)b * H_ + y) * W_ + x) * CH + g * 16;
    *(uint4v*)dst = (uint4v){wd[0], wd[1], wd[2], wd[3]};
}

#define MXMFMA(A, Bv, C) \
    __builtin_amdgcn_mfma_scale_f32_32x32x64_f8f6f4(A, Bv, C, 0, 0, 0, 0x7F, 0, 0x7F)

__global__ __launch_bounds__(512) void nlwa_fp8(
    const float* __restrict__ xlab,
    const unsigned char* __restrict__ tf,
    const float* __restrict__ n2,
    float4* __restrict__ part)        // [B][H][2 q][64 m]
{
    const int b = blockIdx.y, ym = blockIdx.x, q = blockIdx.z;
    const int tid = (int)threadIdx.x;
    const int w = tid >> 6, l = tid & 63;   // EIGHT waves
    const int l31 = l & 31, h = l >> 5;
    const int zh = w >> 2;            // yn-sub-sixteenth within this q
    const int w4 = w & 3;             // wave-in-sub
    const int mt = (w >> 1) & 1, nh = w & 1;
    const int lo = (q << 5) + (zh << 4);   // this sub-group's 16 yn

    __shared__ __attribute__((aligned(16))) char smem[15 * ROWB]; // 2x6 ring + 3 A
    __shared__ float state[2][2][64][4];  // [zh][nh][m]{S,W0,W1,pad}
    __shared__ float mref_lds[64];
    char* ring  = smem + zh * (NRING * ROWB);
    char* aslab = smem + 2 * NRING * ROWB;

    const unsigned char* tfb = tf + (size_t)b * H_ * W_ * CH;
    const float* aab = xlab + ((size_t)b * 3 + 1) * H_ * W_;
    const float* bab = xlab + ((size_t)b * 3 + 2) * H_ * W_;

    // zero pad columns xx=0,65: 15 slabs x 4 stripes x 2 = 120 16B-chunks
    if (tid < 120) {
        int s15 = tid >> 3, rem = tid & 7;
        int which = rem >> 2, t = rem & 3;
        char* base = smem + s15 * ROWB;
        *(uint4v*)(base + t * STRIPE + (which ? 65 * 16 : 0)) = (uint4v){0,0,0,0};
    }
    // zero softmax state (1024 floats over 512 threads)
    #pragma unroll
    for (int i = 0; i < 2; ++i) ((float*)state)[i * 512 + tid] = 0.f;

    // Mref[x] = SCALE2 * 3x3 box-sum of n2 around (ym, x), zero-padded
    if (tid < 64) {
        const float* n2b = n2 + (size_t)b * H_ * W_;
        float s = 0.f;
        #pragma unroll
        for (int dy = -1; dy <= 1; ++dy) {
            int y = ym + dy;
            if ((unsigned)y < H_) {
                #pragma unroll
                for (int dx = -1; dx <= 1; ++dx) {
                    int x = tid + dx;
                    if ((unsigned)x < W_) s += n2b[y * W_ + x];
                }
            }
        }
        mref_lds[tid] = s * SCALE2;
    }

    // stage one (row y, stripe t): async DMA into xx=1..64 (1024 B), or zeros
    auto stage = [&](char* slabBase, int y, int t) {
        char* dst = slabBase + t * STRIPE + 16;
        if ((unsigned)y < H_) {
            const unsigned char* gp = tfb + ((size_t)y * W_ + l) * CH + t * 16;
            glds16(gp, dst);
        } else {
            *(uint4v*)(dst + l * 16) = (uint4v){0, 0, 0, 0};
        }
    };

    // prologue. zh0 group: its ring rows lo-1..lo+2 (16 tasks) + A rows
    // ym-1..ym+1 (12 tasks). zh1 group: its ring rows lo-1..lo+2 (16 tasks).
    if (zh == 0) {
        for (int tau = w4; tau < 28; tau += 4) {
            int r = tau >> 2, t = tau & 3;
            if (r < 4) {
                int y = lo - 1 + r;
                stage(ring + ((y + 1) % NRING) * ROWB, y, t);
            } else {
                int dy = r - 4;
                stage(aslab + dy * ROWB, ym + dy - 1, t);
            }
        }
    } else {
        for (int tau = w4; tau < 16; tau += 4) {
            int r = tau >> 2, t = tau & 3;
            int y = lo - 1 + r;
            stage(ring + ((y + 1) % NRING) * ROWB, y, t);
        }
    }

    const int xn = (nh << 5) + l31;   // lane's n-column
    const int xm = (mt << 5) + l31;   // lane's m-position (A-side)
    const int soL = h * STRIPE;       // stripe g = h     (qq=0 half)
    const int soH = (2 + h) * STRIPE; // stripe g = 2 + h (qq=1 half)

    // 32B MX operand: stripe pair {h, 2+h} at pixel offset -> v8i32
    auto ld32 = [&](const char* slab, int off) -> int8v {
        uint4v r0 = *(const uint4v*)(slab + soL + off);
        uint4v r1 = *(const uint4v*)(slab + soH + off);
        int8v a;
        a[0] = r0[0]; a[1] = r0[1]; a[2] = r0[2]; a[3] = r0[3];
        a[4] = r1[0]; a[5] = r1[1]; a[6] = r1[2]; a[7] = r1[3];
        return a;
    };

    __syncthreads();   // prologue DMAs drained (incl. aslab)

    // ---- A-fragments hoisted to registers: loop-invariant, 9 x int8v ----
    int8v Areg0[3], Areg1[3], Areg2[3];   // [dyi] x [dx], statically unrolled
    #pragma unroll
    for (int dx = 0; dx < 3; ++dx) {
        const int oa = (xm + dx) * 16;
        Areg0[dx] = ld32(aslab + 0 * ROWB, oa);
        Areg1[dx] = ld32(aslab + 1 * ROWB, oa);
        Areg2[dx] = ld32(aslab + 2 * ROWB, oa);
    }

    float Mref[16];
    #pragma unroll
    for (int r = 0; r < 16; ++r)
        Mref[r] = mref_lds[(mt << 5) + (r & 3) + ((r >> 2) << 3) + (h << 2)];

    #pragma unroll 1
    for (int p = 0; p < 8; ++p) {
        const int y0 = lo + (p << 1);

        // async prefetch rows y0+3, y0+4 into this sub-group's ring
        // (working slots (y0..y0+3)%6, prefetch (y0+4,y0+5)%6 -- disjoint)
        if (p < 7) {
            #pragma unroll
            for (int k = 0; k < 2; ++k) {
                int tau = (k << 2) + w4;
                int ri = tau >> 2, t = tau & 3;
                int y = y0 + 3 + ri;
                stage(ring + ((y + 1) % NRING) * ROWB, y, t);
            }
        }

        f32x16 acc0, acc1;
        #pragma unroll
        for (int r = 0; r < 16; ++r) { acc0[r] = 0.f; acc1[r] = 0.f; }

        const char* rb[4];
        #pragma unroll
        for (int j2 = 0; j2 < 4; ++j2)
            rb[j2] = ring + ((y0 + j2) % NRING) * ROWB;   // row y0-1+j2

        #pragma unroll
        for (int dx = 0; dx < 3; ++dx) {
            const int ob = (xn + dx) * 16;
            int8v Bb0 = ld32(rb[0], ob);
            int8v Bb1 = ld32(rb[1], ob);
            int8v Bb2 = ld32(rb[2], ob);
            int8v Bb3 = ld32(rb[3], ob);
            acc0 = MXMFMA(Areg0[dx], Bb0, acc0);
            acc0 = MXMFMA(Areg1[dx], Bb1, acc0);
            acc0 = MXMFMA(Areg2[dx], Bb2, acc0);
            acc1 = MXMFMA(Areg0[dx], Bb1, acc1);
            acc1 = MXMFMA(Areg1[dx], Bb2, acc1);
            acc1 = MXMFMA(Areg2[dx], Bb3, acc1);
        }

        // fixed-reference softmax: guard-gated LDS accumulation (rare path)
        #pragma unroll
        for (int j = 0; j < 2; ++j) {
            const f32x16& ac = (j == 0) ? acc0 : acc1;
            float v[16]; int upd = 0;
            #pragma unroll
            for (int r = 0; r < 16; ++r) {
                v[r] = fmaf(ac[r], SCALE2, -Mref[r]);
                upd |= (v[r] > -30.0f) ? 1 : 0;
            }
            if (__any(upd)) {
                const int yn = y0 + j;
                float av = aab[yn * W_ + xn];
                float bv = bab[yn * W_ + xn];
                #pragma unroll
                for (int r = 0; r < 16; ++r) {
                    float pp  = exp2f(fminf(v[r], 80.0f));
                    float w0c = pp * av;
                    float w1c = pp * bv;
                    #pragma unroll
                    for (int off = 16; off >= 1; off >>= 1) {
                        pp  += __shfl_xor(pp,  off);
                        w0c += __shfl_xor(w0c, off);
                        w1c += __shfl_xor(w1c, off);
                    }
                    if (l31 == 0) {
                        int m = (mt << 5) + (r & 3) + ((r >> 2) << 3) + (h << 2);
                        float* st = &state[zh][nh][m][0];
                        st[0] += pp; st[1] += w0c; st[2] += w1c;
                    }
                }
            }
        }
        __syncthreads();   // stage DMAs drained; ring slots safe; state visible
    }

    // final: sum the 4 partial states, write q-partial
    if (tid < 64) {
        float Ssum = 0.f, w0 = 0.f, w1 = 0.f;
        #pragma unroll
        for (int z2 = 0; z2 < 2; ++z2)
            #pragma unroll
            for (int n2i = 0; n2i < 2; ++n2i) {
                Ssum += state[z2][n2i][tid][0];
                w0   += state[z2][n2i][tid][1];
                w1   += state[z2][n2i][tid][2];
            }
        part[(((size_t)b * H_ + ym) * 2 + q) * 64 + tid] =
            make_float4(Ssum, w0, w1, 0.f);
    }
}

__global__ __launch_bounds__(256) void nlwa_out(
    const float4* __restrict__ part, float* __restrict__ out)
{
    int idx = blockIdx.x * 256 + (int)threadIdx.x;   // 16384 = B*H*64
    int b = idx >> 12, rem = idx & 4095, ym = rem >> 6, m = rem & 63;
    const float4* pb = &part[(((size_t)b * H_ + ym) * 2) * 64 + m];
    float4 P0 = pb[0];
    float4 P1 = pb[64];
    float inv = 1.0f / (P0.x + P1.x);
    out[(((size_t)b * 2 + 0) * H_ + ym) * W_ + m] = (P0.y + P1.y) * inv;
    out[(((size_t)b * 2 + 1) * H_ + ym) * W_ + m] = (P0.z + P1.z) * inv;
}

extern "C" void kernel_launch(void* const* d_in, const int* in_sizes, int n_in,
                              void* d_out, int out_size, void* d_ws, size_t ws_size,
                              hipStream_t stream) {
    const float* xlab = (const float*)d_in[0];
    const float* feat = (const float*)d_in[1];
    float* out = (float*)d_out;
    unsigned char* tf = (unsigned char*)d_ws;                          // 1 MB
    float* n2   = (float*)((char*)d_ws + (size_t)1024 * 1024);         // 64 KB
    float4* part = (float4*)((char*)d_ws + (size_t)1088 * 1024);       // 512 KB

    dim3 gridT(H_, B_);
    feat_to_fp8<<<gridT, 256, 0, stream>>>(feat, tf, n2);
    dim3 gridM(H_, B_, 2);
    nlwa_fp8<<<gridM, 512, 0, stream>>>(xlab, tf, n2, part);
    nlwa_out<<<64, 256, 0, stream>>>(part, out);
}

// Round 21
// 43.245 us; speedup vs baseline: 1.2482x; 1.2482x over previous
//
#include <hip/hip_runtime.h>
#include <math.h>

// NonlocalWeightedAverage via MX-scaled fp8 MFMA (K=64), fixed-reference
// softmax. corr[m,n] = <lf_m, lf_n>, lf = 3x3-unfolded feature, K = 9*64.
// R21: R17's proven body (2-gen sub-SP, A-hoist, 120 VGPR, no spill) with
// HALVED barriers: 10-slot ring per zh, each barrier period = 2 sub-SPs
// (4 gens, rows y0-1..y0+4 = slots (y0..y0+5)%10) + prefetch of rows
// y0+5..y0+8 (slots (y0+6..y0+9)%10, disjoint -- R18's verified map).
// Rationale: true regs (VGPR 116 + unified-file acc AGPRs ~64 = ~180) cap
// residency at 2 waves/SIMD -- all multi-block schemes R10-R20 hit this
// wall; the remaining lever is the ~1200 cyc/SP barrier drain, paid 16x
// in R17, 8x here. Accumulators stay sub-SP-local (no R18 spill).

#define B_ 4
#define CH 64
#define H_ 64
#define W_ 64
#define SCALE2 14.426950408889634f   // (1/ALPHA=10) * log2(e)
#define STRIPE 1056                  // 66 xx * 16 B
#define ROWB (4 * STRIPE)            // 4224 B: one feature row (fp8)
#define NRING 10

typedef __attribute__((ext_vector_type(4)))  unsigned int uint4v;
typedef __attribute__((ext_vector_type(16))) float f32x16;
typedef __attribute__((ext_vector_type(8)))  int int8v;

__device__ inline void glds16(const void* g, void* l) {
    __builtin_amdgcn_global_load_lds(
        (const __attribute__((address_space(1))) unsigned int*)g,
        (__attribute__((address_space(3))) unsigned int*)l, 16, 0, 0);
}

// decode OCP e4m3fn (NaN never occurs for our data: |f| <= ~5 << 448)
__device__ inline float dec_e4m3(unsigned u) {
    unsigned e = (u >> 3) & 15u, m = u & 7u;
    float v = e ? __uint_as_float(((e + 120u) << 23) | (m << 20))
                : (float)m * 0x1p-9f;
    return (u & 0x80u) ? -v : v;
}

// feat [B,C,H,W] f32 -> tf [B,H,W,64] fp8 e4m3 (fragment-pair packed), plus
// per-pixel channel-norm^2 of the DECODED fp8 values -> n2 [B,H,W].
__global__ __launch_bounds__(256) void feat_to_fp8(
    const float* __restrict__ feat, unsigned char* __restrict__ tf,
    float* __restrict__ n2)
{
    const int b = blockIdx.y, y = blockIdx.x, t = (int)threadIdx.x;
    __shared__ float ld[CH][W_ + 1];
    #pragma unroll
    for (int i = 0; i < 16; ++i) {
        int idx = i * 256 + t;
        int c = idx >> 6, x = idx & 63;
        ld[c][x] = feat[(((size_t)b * CH + c) * H_ + y) * W_ + x];
    }
    __syncthreads();
    const int x = t >> 2, g = t & 3;
    const int cbase = (g >> 1) * 32 + (g & 1) * 8;
    unsigned int wd[4];
    #pragma unroll
    for (int w4 = 0; w4 < 4; ++w4) {
        float f[4];
        #pragma unroll
        for (int e = 0; e < 4; ++e) {
            int j = w4 * 4 + e;
            f[e] = ld[cbase + ((j >> 3) << 4) + (j & 7)][x];
        }
        unsigned int wv = 0;
        wv = __builtin_amdgcn_cvt_pk_fp8_f32(f[0], f[1], wv, false);
        wv = __builtin_amdgcn_cvt_pk_fp8_f32(f[2], f[3], wv, true);
        wd[w4] = wv;
    }
    float s = 0.f;
    #pragma unroll
    for (int w4 = 0; w4 < 4; ++w4)
        #pragma unroll
        for (int e = 0; e < 4; ++e) {
            float d = dec_e4m3((wd[w4] >> (8 * e)) & 0xffu);
            s = fmaf(d, d, s);
        }
    s += __shfl_xor(s, 1);
    s += __shfl_xor(s, 2);
    if (g == 0) n2[((size_t)b * H_ + y) * W_ + x] = s;

    unsigned char* dst = tf + (((size_t)b * H_ + y) * W_ + x) * CH + g * 16;
    *(uint4v*)dst = (uint4v){wd[0], wd[1], wd[2], wd[3]};
}

#define MXMFMA(A, Bv, C) \
    __builtin_amdgcn_mfma_scale_f32_32x32x64_f8f6f4(A, Bv, C, 0, 0, 0, 0x7F, 0, 0x7F)

__global__ __launch_bounds__(512) void nlwa_fp8(
    const float* __restrict__ xlab,
    const unsigned char* __restrict__ tf,
    const float* __restrict__ n2,
    float* __restrict__ out)
{
    const int b = blockIdx.y, ym = blockIdx.x;
    const int tid = (int)threadIdx.x;
    const int w = tid >> 6, l = tid & 63;   // EIGHT waves
    const int l31 = l & 31, h = l >> 5;
    const int zh = w >> 2;            // yn-half: [0,32) or [32,64)
    const int w4 = w & 3;             // wave-in-half
    const int mt = (w >> 1) & 1, nh = w & 1;
    const int lo = zh << 5;

    __shared__ __attribute__((aligned(16))) char smem[23 * ROWB]; // 2x10 ring + 3 A
    __shared__ float state[2][2][64][4];  // [zh][nh][m]{S,W0,W1,pad}
    __shared__ float mref_lds[64];
    char* ring  = smem + zh * (NRING * ROWB);
    char* aslab = smem + 2 * NRING * ROWB;

    const unsigned char* tfb = tf + (size_t)b * H_ * W_ * CH;
    const float* aab = xlab + ((size_t)b * 3 + 1) * H_ * W_;
    const float* bab = xlab + ((size_t)b * 3 + 2) * H_ * W_;

    // zero pad columns xx=0,65: 23 slabs x 4 stripes x 2 = 184 16B-chunks
    if (tid < 184) {
        int s23 = tid >> 3, rem = tid & 7;
        int which = rem >> 2, t = rem & 3;
        char* base = smem + s23 * ROWB;
        *(uint4v*)(base + t * STRIPE + (which ? 65 * 16 : 0)) = (uint4v){0,0,0,0};
    }
    // zero softmax state (1024 floats over 512 threads)
    #pragma unroll
    for (int i = 0; i < 2; ++i) ((float*)state)[i * 512 + tid] = 0.f;

    // Mref[x] = SCALE2 * 3x3 box-sum of n2 around (ym, x), zero-padded
    if (tid < 64) {
        const float* n2b = n2 + (size_t)b * H_ * W_;
        float s = 0.f;
        #pragma unroll
        for (int dy = -1; dy <= 1; ++dy) {
            int y = ym + dy;
            if ((unsigned)y < H_) {
                #pragma unroll
                for (int dx = -1; dx <= 1; ++dx) {
                    int x = tid + dx;
                    if ((unsigned)x < W_) s += n2b[y * W_ + x];
                }
            }
        }
        mref_lds[tid] = s * SCALE2;
    }

    // stage one (row y, stripe t): async DMA into xx=1..64 (1024 B), or zeros
    auto stage = [&](char* slabBase, int y, int t) {
        char* dst = slabBase + t * STRIPE + 16;
        if ((unsigned)y < H_) {
            const unsigned char* gp = tfb + ((size_t)y * W_ + l) * CH + t * 16;
            glds16(gp, dst);
        } else {
            *(uint4v*)(dst + l * 16) = (uint4v){0, 0, 0, 0};
        }
    };

    // prologue (R18's verified map). zh0: ring rows lo-1..lo+4 (24 tasks) +
    // A rows ym-1..ym+1 (12 tasks) = 36. zh1: ring rows lo-1..lo+4 (24).
    if (zh == 0) {
        for (int tau = w4; tau < 36; tau += 4) {
            int r = tau >> 2, t = tau & 3;
            if (r < 6) {
                int y = lo - 1 + r;
                stage(ring + ((y + 1) % NRING) * ROWB, y, t);
            } else {
                int dy = r - 6;
                stage(aslab + dy * ROWB, ym + dy - 1, t);
            }
        }
    } else {
        for (int tau = w4; tau < 24; tau += 4) {
            int r = tau >> 2, t = tau & 3;
            int y = lo - 1 + r;
            stage(ring + ((y + 1) % NRING) * ROWB, y, t);
        }
    }

    const int xn = (nh << 5) + l31;   // lane's n-column
    const int xm = (mt << 5) + l31;   // lane's m-position (A-side)
    const int soL = h * STRIPE;       // stripe g = h     (qq=0 half)
    const int soH = (2 + h) * STRIPE; // stripe g = 2 + h (qq=1 half)

    // 32B MX operand: stripe pair {h, 2+h} at pixel offset -> v8i32
    auto ld32 = [&](const char* slab, int off) -> int8v {
        uint4v r0 = *(const uint4v*)(slab + soL + off);
        uint4v r1 = *(const uint4v*)(slab + soH + off);
        int8v a;
        a[0] = r0[0]; a[1] = r0[1]; a[2] = r0[2]; a[3] = r0[3];
        a[4] = r1[0]; a[5] = r1[1]; a[6] = r1[2]; a[7] = r1[3];
        return a;
    };

    __syncthreads();   // prologue DMAs drained (incl. aslab)

    // ---- A-fragments hoisted to registers: loop-invariant, 9 x int8v ----
    int8v Areg0[3], Areg1[3], Areg2[3];   // [dyi] x [dx], statically unrolled
    #pragma unroll
    for (int dx = 0; dx < 3; ++dx) {
        const int oa = (xm + dx) * 16;
        Areg0[dx] = ld32(aslab + 0 * ROWB, oa);
        Areg1[dx] = ld32(aslab + 1 * ROWB, oa);
        Areg2[dx] = ld32(aslab + 2 * ROWB, oa);
    }

    float Mref[16];
    #pragma unroll
    for (int r = 0; r < 16; ++r)
        Mref[r] = mref_lds[(mt << 5) + (r & 3) + ((r >> 2) << 3) + (h << 2)];

    // 8 barrier periods; each = 4-row prefetch + TWO 2-gen sub-superphases.
    #pragma unroll 1
    for (int p = 0; p < 8; ++p) {
        const int y0 = lo + (p << 2);

        // async prefetch rows y0+5..y0+8 -> slots (y0+6..y0+9)%10, disjoint
        // from this period's working slots (y0..y0+5)%10. 16 tasks over 4
        // waves: wave w4 stages stripe w4 of each of the 4 rows.
        if (p < 7) {
            #pragma unroll
            for (int k = 0; k < 4; ++k) {
                int y = y0 + 5 + k;
                stage(ring + ((y + 1) % NRING) * ROWB, y, w4);
            }
        }

        #pragma unroll
        for (int s = 0; s < 2; ++s) {
            const int yb = y0 + (s << 1);   // gens yb, yb+1

            f32x16 acc0, acc1;
            #pragma unroll
            for (int r = 0; r < 16; ++r) { acc0[r] = 0.f; acc1[r] = 0.f; }

            const char* rb[4];
            #pragma unroll
            for (int j2 = 0; j2 < 4; ++j2)
                rb[j2] = ring + ((yb + j2) % NRING) * ROWB;   // row yb-1+j2

            #pragma unroll
            for (int dx = 0; dx < 3; ++dx) {
                const int ob = (xn + dx) * 16;
                int8v Bb0 = ld32(rb[0], ob);
                int8v Bb1 = ld32(rb[1], ob);
                int8v Bb2 = ld32(rb[2], ob);
                int8v Bb3 = ld32(rb[3], ob);
                acc0 = MXMFMA(Areg0[dx], Bb0, acc0);
                acc0 = MXMFMA(Areg1[dx], Bb1, acc0);
                acc0 = MXMFMA(Areg2[dx], Bb2, acc0);
                acc1 = MXMFMA(Areg0[dx], Bb1, acc1);
                acc1 = MXMFMA(Areg1[dx], Bb2, acc1);
                acc1 = MXMFMA(Areg2[dx], Bb3, acc1);
            }

            // fixed-reference softmax: guard-gated LDS accumulation
            #pragma unroll
            for (int j = 0; j < 2; ++j) {
                const f32x16& ac = (j == 0) ? acc0 : acc1;
                float v[16]; int upd = 0;
                #pragma unroll
                for (int r = 0; r < 16; ++r) {
                    v[r] = fmaf(ac[r], SCALE2, -Mref[r]);
                    upd |= (v[r] > -30.0f) ? 1 : 0;
                }
                if (__any(upd)) {
                    const int yn = yb + j;
                    float av = aab[yn * W_ + xn];
                    float bv = bab[yn * W_ + xn];
                    #pragma unroll
                    for (int r = 0; r < 16; ++r) {
                        float pp  = exp2f(fminf(v[r], 80.0f));
                        float w0c = pp * av;
                        float w1c = pp * bv;
                        #pragma unroll
                        for (int off = 16; off >= 1; off >>= 1) {
                            pp  += __shfl_xor(pp,  off);
                            w0c += __shfl_xor(w0c, off);
                            w1c += __shfl_xor(w1c, off);
                        }
                        if (l31 == 0) {
                            int m = (mt << 5) + (r & 3) + ((r >> 2) << 3) + (h << 2);
                            float* st = &state[zh][nh][m][0];
                            st[0] += pp; st[1] += w0c; st[2] += w1c;
                        }
                    }
                }
            }
        }
        __syncthreads();   // period DMAs drained; slots rotate; state visible
    }

    // final: sum the 4 partial states, write output directly
    if (tid < 64) {
        float Ssum = 0.f, w0 = 0.f, w1 = 0.f;
        #pragma unroll
        for (int z2 = 0; z2 < 2; ++z2)
            #pragma unroll
            for (int n2i = 0; n2i < 2; ++n2i) {
                Ssum += state[z2][n2i][tid][0];
                w0   += state[z2][n2i][tid][1];
                w1   += state[z2][n2i][tid][2];
            }
        float inv = 1.0f / Ssum;
        out[(((size_t)b * 2 + 0) * H_ + ym) * W_ + tid] = w0 * inv;
        out[(((size_t)b * 2 + 1) * H_ + ym) * W_ + tid] = w1 * inv;
    }
}

extern "C" void kernel_launch(void* const* d_in, const int* in_sizes, int n_in,
                              void* d_out, int out_size, void* d_ws, size_t ws_size,
                              hipStream_t stream) {
    const float* xlab = (const float*)d_in[0];
    const float* feat = (const float*)d_in[1];
    float* out = (float*)d_out;
    unsigned char* tf = (unsigned char*)d_ws;                          // 1 MB
    float* n2   = (float*)((char*)d_ws + (size_t)1024 * 1024);         // 64 KB

    dim3 gridT(H_, B_);
    feat_to_fp8<<<gridT, 256, 0, stream>>>(feat, tf, n2);
    dim3 gridM(H_, B_);
    nlwa_fp8<<<gridM, 512, 0, stream>>>(xlab, tf, n2, out);
}